// Round 1
// baseline (2544.550 us; speedup 1.0000x reference)
//
#include <hip/hip_runtime.h>
#include <hip/hip_bf16.h>
#include <hip/hip_cooperative_groups.h>

namespace cg = cooperative_groups;

#define VOCAB 10000
#define HID   512
#define BATCH 64
#define SEQ   128
#define NPAD  10240   // padded vocab rows for B^T (zero-filled tail)
#define LDK   40      // LDS k-stride in elems (80 B) -> spreads b128 reads over banks

typedef __attribute__((ext_vector_type(8))) short bf16x8;
typedef __attribute__((ext_vector_type(4))) float f32x4;
typedef __hip_bfloat16 bf16;

// ---------- prep: transpose fp32 [512][N] row-major -> bf16 [NP][512] ----------
__global__ void transpose_to_bf16(const float* __restrict__ src,
                                  bf16* __restrict__ dst, int N, int NP) {
  __shared__ float tile[64][65];
  int n0 = blockIdx.x * 64, k0 = blockIdx.y * 64;
  int c = threadIdx.x & 63, rb = threadIdx.x >> 6;
#pragma unroll
  for (int i = 0; i < 16; ++i) {
    int r = i * 4 + rb;               // k-local
    int n = n0 + c;                   // n-local = c
    tile[r][c] = (n < N) ? src[(size_t)(k0 + r) * N + n] : 0.0f;
  }
  __syncthreads();
#pragma unroll
  for (int i = 0; i < 16; ++i) {
    int rn = i * 4 + rb;              // n-local
    int n = n0 + rn;
    if (n < NP) dst[(size_t)n * HID + k0 + c] = __float2bfloat16(tile[c][rn]);
  }
}

// ---------- prep: H slot 0 = bf16(state) ----------
__global__ void init_h0(const float* __restrict__ state, bf16* __restrict__ H) {
  int i = blockIdx.x * 256 + threadIdx.x;
  H[i] = __float2bfloat16(state[i]);
}

// ---------- recurrence: 32 blocks x 256 threads, cooperative ----------
// block b: gate-columns j0..j0+15 for ALL 4 gates, ALL 64 batch rows.
// wave w = m-subtile (rows 16w..16w+15) for compute, = gate index for B staging.
__global__ void __launch_bounds__(256)
lstm_recurrence(const int* __restrict__ x,
                const float* __restrict__ cell0,
                const bf16* __restrict__ WTg,   // [4*512][512]  (gate-major, [n][k])
                const float* __restrict__ Wxi, const float* __restrict__ Wxf,
                const float* __restrict__ Wxo, const float* __restrict__ Wxc,
                const float* __restrict__ bi_, const float* __restrict__ bf_,
                const float* __restrict__ bo_, const float* __restrict__ bc_,
                bf16* __restrict__ H,           // [129*64][512]
                float* __restrict__ out_state, float* __restrict__ out_cell) {
  __shared__ __align__(16) bf16 Al[BATCH * LDK];   // h  BK=32 slice
  __shared__ __align__(16) bf16 Bl[64 * LDK];      // W  BK=32 slice (4 gates x 16 cols)
  __shared__ int xl[BATCH * SEQ];

  cg::grid_group grid = cg::this_grid();

  const int tid = threadIdx.x;
  const int w = tid >> 6, l = tid & 63;
  const int lc = l & 15, lq = l >> 4;   // frag col / quad
  const int sr = l >> 2, sc = l & 3;    // staging row-in-16 / 16B-chunk
  const int j0 = blockIdx.x * 16;
  const int colg = j0 + lc;             // column within gate

  for (int i = tid; i < BATCH * SEQ; i += 256) xl[i] = x[i];

  const float bias[4] = { bi_[colg], bf_[colg], bo_[colg], bc_[colg] };
  const float* Wx[4] = { Wxi, Wxf, Wxo, Wxc };

  const int brow = w * 16 + lq * 4;     // first of this lane's 4 batch rows
  float cc[4];
#pragma unroll
  for (int r = 0; r < 4; ++r) cc[r] = cell0[(brow + r) * HID + colg];

  __syncthreads();

  for (int t = 0; t < SEQ; ++t) {
    // prefetch Wx gathers early; kk-loop hides their latency
    int tok[4];
    float wx[4][4];
#pragma unroll
    for (int r = 0; r < 4; ++r) tok[r] = xl[(brow + r) * SEQ + t];
#pragma unroll
    for (int g = 0; g < 4; ++g)
#pragma unroll
      for (int r = 0; r < 4; ++r)
        wx[g][r] = Wx[g][(size_t)tok[r] * HID + colg];

    f32x4 acc[4] = {};
    const bf16* Asrc = H + ((size_t)t * BATCH + w * 16 + sr) * HID + sc * 8;
    const bf16* Bsrc = WTg + ((size_t)(w * 512 + j0 + sr)) * HID + sc * 8;

    for (int kk = 0; kk < HID; kk += 32) {
      bf16x8 av = *(const bf16x8*)(Asrc + kk);
      bf16x8 bv = *(const bf16x8*)(Bsrc + kk);
      __syncthreads();                       // protect LDS from prior frag reads
      *(bf16x8*)(&Al[(w * 16 + sr) * LDK + sc * 8]) = av;
      *(bf16x8*)(&Bl[(w * 16 + sr) * LDK + sc * 8]) = bv;
      __syncthreads();
      bf16x8 af = *(const bf16x8*)(&Al[(w * 16 + lc) * LDK + lq * 8]);
#pragma unroll
      for (int g = 0; g < 4; ++g) {
        bf16x8 bfv = *(const bf16x8*)(&Bl[(g * 16 + lc) * LDK + lq * 8]);
        acc[g] = __builtin_amdgcn_mfma_f32_16x16x32_bf16(af, bfv, acc[g], 0, 0, 0);
      }
    }

    // epilogue: gates -> cell update -> h (C/D layout: row=(l>>4)*4+r, col=l&15)
#pragma unroll
    for (int r = 0; r < 4; ++r) {
      float pi = acc[0][r] + bias[0] + wx[0][r];
      float pf = acc[1][r] + bias[1] + wx[1][r];
      float po = acc[2][r] + bias[2] + wx[2][r];
      float pg = acc[3][r] + bias[3] + wx[3][r];
      float gi = 1.0f / (1.0f + __expf(-pi));
      float gf = 1.0f / (1.0f + __expf(-pf));
      float go = 1.0f / (1.0f + __expf(-po));
      float eg = __expf(2.0f * pg);
      float gg = (eg - 1.0f) / (eg + 1.0f);
      float cn = gf * cc[r] + gi * gg;
      cc[r] = cn;
      float ec = __expf(2.0f * cn);
      float th = (ec - 1.0f) / (ec + 1.0f);
      float h = go * th;
      H[((size_t)(t + 1) * BATCH + brow + r) * HID + colg] = __float2bfloat16(h);
      if (t == SEQ - 1) {
        out_state[(brow + r) * HID + colg] = h;
        out_cell [(brow + r) * HID + colg] = cn;
      }
    }
    __threadfence();
    grid.sync();
  }
}

// ---------- batched output GEMM: [8192][512] x [512][10000] + b_q ----------
__global__ void __launch_bounds__(256)
gemm_out(const bf16* __restrict__ A,    // H + 64*512
         const bf16* __restrict__ Bt,   // WT_hq [NPAD][512]
         const float* __restrict__ bq,
         float* __restrict__ out) {
  __shared__ __align__(16) bf16 Al[128 * LDK];
  __shared__ __align__(16) bf16 Bl[128 * LDK];
  const int tid = threadIdx.x;
  const int w = tid >> 6, l = tid & 63;
  const int lc = l & 15, lq = l >> 4;
  const int sr = l >> 2, sc = l & 3;
  const int wm = w >> 1, wn = w & 1;
  const int m0 = blockIdx.y * 128, n0 = blockIdx.x * 128;

  f32x4 acc[4][4] = {};

  const bf16* Asrc = A + (size_t)(m0 + w * 32 + sr) * HID + sc * 8;
  const bf16* Bsrc = Bt + (size_t)(n0 + w * 32 + sr) * HID + sc * 8;

  for (int kk = 0; kk < HID; kk += 32) {
    bf16x8 a0 = *(const bf16x8*)(Asrc + kk);
    bf16x8 a1 = *(const bf16x8*)(Asrc + 16 * HID + kk);
    bf16x8 b0 = *(const bf16x8*)(Bsrc + kk);
    bf16x8 b1 = *(const bf16x8*)(Bsrc + 16 * HID + kk);
    __syncthreads();
    *(bf16x8*)(&Al[(w * 32 + sr) * LDK + sc * 8]) = a0;
    *(bf16x8*)(&Al[(w * 32 + 16 + sr) * LDK + sc * 8]) = a1;
    *(bf16x8*)(&Bl[(w * 32 + sr) * LDK + sc * 8]) = b0;
    *(bf16x8*)(&Bl[(w * 32 + 16 + sr) * LDK + sc * 8]) = b1;
    __syncthreads();
    bf16x8 af[4], bfv[4];
#pragma unroll
    for (int i = 0; i < 4; ++i) {
      af[i]  = *(const bf16x8*)(&Al[(wm * 64 + i * 16 + lc) * LDK + lq * 8]);
      bfv[i] = *(const bf16x8*)(&Bl[(wn * 64 + i * 16 + lc) * LDK + lq * 8]);
    }
#pragma unroll
    for (int i = 0; i < 4; ++i)
#pragma unroll
      for (int j = 0; j < 4; ++j)
        acc[i][j] = __builtin_amdgcn_mfma_f32_16x16x32_bf16(af[i], bfv[j], acc[i][j], 0, 0, 0);
  }

#pragma unroll
  for (int j = 0; j < 4; ++j) {
    int col = n0 + wn * 64 + j * 16 + lc;
    if (col < VOCAB) {
      float bqv = bq[col];
#pragma unroll
      for (int i = 0; i < 4; ++i) {
        int row = m0 + wm * 64 + i * 16 + lq * 4;
#pragma unroll
        for (int r = 0; r < 4; ++r)
          out[(size_t)(row + r) * VOCAB + col] = acc[i][j][r] + bqv;
      }
    }
  }
}

extern "C" void kernel_launch(void* const* d_in, const int* in_sizes, int n_in,
                              void* d_out, int out_size, void* d_ws, size_t ws_size,
                              hipStream_t stream) {
  const int*   x     = (const int*)  d_in[0];
  const float* state = (const float*)d_in[1];
  const float* cell  = (const float*)d_in[2];
  const float* W_xi  = (const float*)d_in[3];
  const float* W_hi  = (const float*)d_in[4];
  const float* b_i   = (const float*)d_in[5];
  const float* W_xf  = (const float*)d_in[6];
  const float* W_hf  = (const float*)d_in[7];
  const float* b_f   = (const float*)d_in[8];
  const float* W_xo  = (const float*)d_in[9];
  const float* W_ho  = (const float*)d_in[10];
  const float* b_o   = (const float*)d_in[11];
  const float* W_xc  = (const float*)d_in[12];
  const float* W_hc  = (const float*)d_in[13];
  const float* b_c   = (const float*)d_in[14];
  const float* W_hq  = (const float*)d_in[15];
  const float* b_q   = (const float*)d_in[16];
  float* out = (float*)d_out;

  char* ws = (char*)d_ws;
  bf16* WT_hq = (bf16*)(ws);                                         // NPAD*512
  bf16* WT_g  = (bf16*)(ws + (size_t)NPAD * HID * 2);                // 4*512*512
  bf16* H     = (bf16*)(ws + (size_t)NPAD * HID * 2 + (size_t)4 * HID * HID * 2); // 129*64*512

  transpose_to_bf16<<<dim3(NPAD / 64, 8), 256, 0, stream>>>(W_hq, WT_hq, VOCAB, NPAD);
  transpose_to_bf16<<<dim3(8, 8), 256, 0, stream>>>(W_hi, WT_g + 0 * HID * HID, HID, HID);
  transpose_to_bf16<<<dim3(8, 8), 256, 0, stream>>>(W_hf, WT_g + 1 * HID * HID, HID, HID);
  transpose_to_bf16<<<dim3(8, 8), 256, 0, stream>>>(W_ho, WT_g + 2 * HID * HID, HID, HID);
  transpose_to_bf16<<<dim3(8, 8), 256, 0, stream>>>(W_hc, WT_g + 3 * HID * HID, HID, HID);
  init_h0<<<dim3(BATCH * HID / 256), 256, 0, stream>>>(state, H);

  float* out_state = out + (size_t)SEQ * BATCH * VOCAB;
  float* out_cell  = out_state + BATCH * HID;

  void* args[] = { (void*)&x, (void*)&cell, (void*)&WT_g,
                   (void*)&W_xi, (void*)&W_xf, (void*)&W_xo, (void*)&W_xc,
                   (void*)&b_i, (void*)&b_f, (void*)&b_o, (void*)&b_c,
                   (void*)&H, (void*)&out_state, (void*)&out_cell };
  hipLaunchCooperativeKernel((void*)lstm_recurrence, dim3(32), dim3(256), args, 0, stream);

  // 79 n-tiles of 128 cover 10112 >= 10000 valid columns (skip the all-dead tile)
  gemm_out<<<dim3(79, SEQ * BATCH / 128), 256, 0, stream>>>(H + BATCH * HID, WT_hq, b_q, out);
}

// Round 2
// 1817.470 us; speedup vs baseline: 1.4001x; 1.4001x over previous
//
#include <hip/hip_runtime.h>
#include <hip/hip_bf16.h>

#define VOCAB 10000
#define HID   512
#define BATCH 64
#define SEQ   128
#define NPAD  10240   // padded vocab rows for B^T (zero-filled tail)

typedef __attribute__((ext_vector_type(8))) short bf16x8;
typedef __attribute__((ext_vector_type(4))) float f32x4;
typedef __hip_bfloat16 bf16;
typedef const __attribute__((address_space(1))) short gshort;
typedef __attribute__((address_space(3))) short lshort;

// async global->LDS, 16B per lane, LDS dest = wave-uniform base + lane*16
__device__ static inline void gload_lds16(const bf16* g, bf16* l) {
  __builtin_amdgcn_global_load_lds((gshort*)g, (lshort*)l, 16, 0, 0);
}

// ---------- prep: transpose fp32 [512][N] row-major -> bf16 [NP][512] ----------
__global__ void transpose_to_bf16(const float* __restrict__ src,
                                  bf16* __restrict__ dst, int N, int NP) {
  __shared__ float tile[64][65];
  int n0 = blockIdx.x * 64, k0 = blockIdx.y * 64;
  int c = threadIdx.x & 63, rb = threadIdx.x >> 6;
#pragma unroll
  for (int i = 0; i < 16; ++i) {
    int r = i * 4 + rb;
    int n = n0 + c;
    tile[r][c] = (n < N) ? src[(size_t)(k0 + r) * N + n] : 0.0f;
  }
  __syncthreads();
#pragma unroll
  for (int i = 0; i < 16; ++i) {
    int rn = i * 4 + rb;
    int n = n0 + rn;
    if (n < NP) dst[(size_t)n * HID + k0 + c] = __float2bfloat16(tile[c][rn]);
  }
}

// ---------- prep: H slot 0 = bf16(state) ----------
__global__ void init_h0(const float* __restrict__ state, bf16* __restrict__ H) {
  int i = blockIdx.x * 256 + threadIdx.x;
  H[i] = __float2bfloat16(state[i]);
}

// ---------- recurrence: 32 blocks x 256 threads, cooperative ----------
// block b: gate-columns j0..j0+15 for ALL 4 gates, ALL 64 batch rows.
// LDS layout (both A and B): row-major, 64 chunks of 16B per row, chunk c of
// row r stored at slot c ^ (r&7)  -> global_load_lds-compatible (contiguous
// 1024B rows) AND 2-way-max bank conflicts on frag ds_read_b128 (free, m136).
__global__ void __launch_bounds__(256)
lstm_recurrence(const int* __restrict__ x,
                const float* __restrict__ cell0,
                const bf16* __restrict__ WTg,   // [4*512][512]  (gate-major, [n][k])
                const float* __restrict__ Wxi, const float* __restrict__ Wxf,
                const float* __restrict__ Wxo, const float* __restrict__ Wxc,
                const float* __restrict__ bi_, const float* __restrict__ bf_,
                const float* __restrict__ bo_, const float* __restrict__ bc_,
                bf16* __restrict__ H,           // [129*64][512]
                float* __restrict__ out_state, float* __restrict__ out_cell,
                unsigned* __restrict__ bar) {
  __shared__ __align__(16) bf16 Al[BATCH * HID];   // 64 KB  h tile (swizzled)
  __shared__ __align__(16) bf16 Bl[64 * HID];      // 64 KB  W slice (swizzled)

  const int tid = threadIdx.x;
  const int w = tid >> 6, l = tid & 63;
  const int lc = l & 15, lq = l >> 4;     // frag col / quad
  const int j0 = blockIdx.x * 16;
  const int colg = j0 + lc;               // column within gate
  const int brow = w * 16 + lq * 4;       // first of this lane's 4 batch rows

  // stage W slice ONCE: wave w -> gate w, LDS rows w*16+n  (n = col-in-block)
#pragma unroll
  for (int n = 0; n < 16; ++n) {
    int row = w * 16 + n;
    const bf16* g = WTg + ((size_t)(w * HID + j0 + n)) * HID + ((l ^ (row & 7)) * 8);
    gload_lds16(g, &Bl[row * HID]);
  }

  const float bias[4] = { bi_[colg], bf_[colg], bo_[colg], bc_[colg] };
  float cc[4];
#pragma unroll
  for (int r = 0; r < 4; ++r) cc[r] = cell0[(brow + r) * HID + colg];

  __syncthreads();   // drains vmcnt for B staging

#pragma unroll 1
  for (int t = 0; t < SEQ; ++t) {
    // token + embedding-row gather prefetch (consumed only in epilogue)
    int tok[4];
#pragma unroll
    for (int r = 0; r < 4; ++r) tok[r] = x[(brow + r) * SEQ + t];
    float wx[4][4];
#pragma unroll
    for (int r = 0; r < 4; ++r) {
      wx[0][r] = Wxi[(size_t)tok[r] * HID + colg];
      wx[1][r] = Wxf[(size_t)tok[r] * HID + colg];
      wx[2][r] = Wxo[(size_t)tok[r] * HID + colg];
      wx[3][r] = Wxc[(size_t)tok[r] * HID + colg];
    }

    // stage A = h_t (64x512 bf16), wave w covers rows w*16..w*16+15
    const bf16* hsrc = H + (size_t)t * BATCH * HID;
#pragma unroll
    for (int n = 0; n < 16; ++n) {
      int row = w * 16 + n;
      const bf16* g = hsrc + (size_t)row * HID + ((l ^ (row & 7)) * 8);
      gload_lds16(g, &Al[row * HID]);
    }
    __syncthreads();   // drains vmcnt: A tile ready

    f32x4 acc[4] = {};
    const int swz = (lc & 7);
#pragma unroll
    for (int kk = 0; kk < 16; ++kk) {          // K = 16 x 32
      int off = ((kk * 4 + lq) ^ swz) * 8;     // chunk (kk*4+lq), swizzled
      bf16x8 af = *(const bf16x8*)&Al[(w * 16 + lc) * HID + off];
#pragma unroll
      for (int g = 0; g < 4; ++g) {
        bf16x8 bv = *(const bf16x8*)&Bl[(g * 16 + lc) * HID + off];
        acc[g] = __builtin_amdgcn_mfma_f32_16x16x32_bf16(af, bv, acc[g], 0, 0, 0);
      }
    }

    // epilogue: gates -> cell update -> h   (C/D: row=brow+r, col=colg)
#pragma unroll
    for (int r = 0; r < 4; ++r) {
      float pi = acc[0][r] + bias[0] + wx[0][r];
      float pf = acc[1][r] + bias[1] + wx[1][r];
      float po = acc[2][r] + bias[2] + wx[2][r];
      float pg = acc[3][r] + bias[3] + wx[3][r];
      float gi = 1.0f / (1.0f + __expf(-pi));
      float gf = 1.0f / (1.0f + __expf(-pf));
      float go = 1.0f / (1.0f + __expf(-po));
      float eg = __expf(2.0f * pg);
      float gg = (eg - 1.0f) / (eg + 1.0f);
      float cn = gf * cc[r] + gi * gg;
      cc[r] = cn;
      float ec = __expf(2.0f * cn);
      float th = (ec - 1.0f) / (ec + 1.0f);
      float h = go * th;
      H[((size_t)(t + 1) * BATCH + brow + r) * HID + colg] = __float2bfloat16(h);
      if (t == SEQ - 1) {
        out_state[(brow + r) * HID + colg] = h;
        out_cell [(brow + r) * HID + colg] = cn;
      }
    }

    if (t < SEQ - 1) {
      // release h writes, then monotonic device-scope barrier
      __threadfence();
      __syncthreads();                       // all threads' fences done; LDS reads done
      if (tid == 0) {
        atomicAdd(bar, 1u);                  // device-scope by default
        while (__atomic_load_n(bar, __ATOMIC_RELAXED) < 32u * (unsigned)(t + 1)) {}
      }
      __syncthreads();
      __threadfence();                       // acquire: invalidate L1/L2 before reading H_{t+1}
    }
  }
}

// ---------- batched output GEMM: [8192][512] x [512][10000] + b_q ----------
// 128x128 tile, BK=64, global_load_lds staging with the same XOR swizzle.
__global__ void __launch_bounds__(256)
gemm_out(const bf16* __restrict__ A,    // H + 64*512
         const bf16* __restrict__ Bt,   // WT_hq [NPAD][512]
         const float* __restrict__ bq,
         float* __restrict__ out) {
  __shared__ __align__(16) bf16 Al[128 * 64];   // 16 KB, rows of 8 chunks (swizzled)
  __shared__ __align__(16) bf16 Bl[128 * 64];
  const int tid = threadIdx.x;
  const int w = tid >> 6, l = tid & 63;
  const int lc = l & 15, lq = l >> 4;
  const int wm = w >> 1, wn = w & 1;
  const int ri = l >> 3, cj = l & 7;            // staging row-in-8 / chunk
  const int m0 = blockIdx.y * 128, n0 = blockIdx.x * 128;

  f32x4 acc[4][4] = {};
  const int swz = (lc & 7);

  for (int kk = 0; kk < HID; kk += 64) {
    __syncthreads();                            // prev iter's frag reads done
    // wave w stages A rows [w*32, w*32+32) and B rows [w*32, w*32+32)
#pragma unroll
    for (int n = 0; n < 4; ++n) {
      int row = w * 32 + n * 8 + ri;            // row&7 == ri
      const bf16* ga = A  + (size_t)(m0 + row) * HID + kk + ((cj ^ ri) * 8);
      gload_lds16(ga, &Al[(w * 32 + n * 8) * 64]);
      const bf16* gb = Bt + (size_t)(n0 + row) * HID + kk + ((cj ^ ri) * 8);
      gload_lds16(gb, &Bl[(w * 32 + n * 8) * 64]);
    }
    __syncthreads();                            // vmcnt drained: tiles ready
#pragma unroll
    for (int ks = 0; ks < 2; ++ks) {
      int off = ((ks * 4 + lq) ^ swz) * 8;
      bf16x8 af[4], bv[4];
#pragma unroll
      for (int i = 0; i < 4; ++i) {
        af[i] = *(const bf16x8*)&Al[(wm * 64 + i * 16 + lc) * 64 + off];
        bv[i] = *(const bf16x8*)&Bl[(wn * 64 + i * 16 + lc) * 64 + off];
      }
#pragma unroll
      for (int i = 0; i < 4; ++i)
#pragma unroll
        for (int j = 0; j < 4; ++j)
          acc[i][j] = __builtin_amdgcn_mfma_f32_16x16x32_bf16(af[i], bv[j], acc[i][j], 0, 0, 0);
    }
  }

#pragma unroll
  for (int j = 0; j < 4; ++j) {
    int col = n0 + wn * 64 + j * 16 + lc;
    if (col < VOCAB) {
      float bqv = bq[col];
#pragma unroll
      for (int i = 0; i < 4; ++i) {
        int row = m0 + wm * 64 + i * 16 + lq * 4;
#pragma unroll
        for (int r = 0; r < 4; ++r)
          out[(size_t)(row + r) * VOCAB + col] = acc[i][j][r] + bqv;
      }
    }
  }
}

extern "C" void kernel_launch(void* const* d_in, const int* in_sizes, int n_in,
                              void* d_out, int out_size, void* d_ws, size_t ws_size,
                              hipStream_t stream) {
  const int*   x     = (const int*)  d_in[0];
  const float* state = (const float*)d_in[1];
  const float* cell  = (const float*)d_in[2];
  const float* W_xi  = (const float*)d_in[3];
  const float* W_hi  = (const float*)d_in[4];
  const float* b_i   = (const float*)d_in[5];
  const float* W_xf  = (const float*)d_in[6];
  const float* W_hf  = (const float*)d_in[7];
  const float* b_f   = (const float*)d_in[8];
  const float* W_xo  = (const float*)d_in[9];
  const float* W_ho  = (const float*)d_in[10];
  const float* b_o   = (const float*)d_in[11];
  const float* W_xc  = (const float*)d_in[12];
  const float* W_hc  = (const float*)d_in[13];
  const float* b_c   = (const float*)d_in[14];
  const float* W_hq  = (const float*)d_in[15];
  const float* b_q   = (const float*)d_in[16];
  float* out = (float*)d_out;

  char* ws = (char*)d_ws;
  bf16* WT_hq = (bf16*)(ws);                                          // NPAD*512
  bf16* WT_g  = (bf16*)(ws + (size_t)NPAD * HID * 2);                 // 4*512*512
  bf16* H     = (bf16*)(ws + (size_t)NPAD * HID * 2 + (size_t)4 * HID * HID * 2); // 129*64*512
  unsigned* bar = (unsigned*)(ws + (size_t)NPAD * HID * 2
                                 + (size_t)4 * HID * HID * 2
                                 + (size_t)129 * BATCH * HID * 2);

  transpose_to_bf16<<<dim3(NPAD / 64, 8), 256, 0, stream>>>(W_hq, WT_hq, VOCAB, NPAD);
  transpose_to_bf16<<<dim3(8, 8), 256, 0, stream>>>(W_hi, WT_g + 0 * HID * HID, HID, HID);
  transpose_to_bf16<<<dim3(8, 8), 256, 0, stream>>>(W_hf, WT_g + 1 * HID * HID, HID, HID);
  transpose_to_bf16<<<dim3(8, 8), 256, 0, stream>>>(W_ho, WT_g + 2 * HID * HID, HID, HID);
  transpose_to_bf16<<<dim3(8, 8), 256, 0, stream>>>(W_hc, WT_g + 3 * HID * HID, HID, HID);
  init_h0<<<dim3(BATCH * HID / 256), 256, 0, stream>>>(state, H);
  hipMemsetAsync(bar, 0, 128, stream);

  float* out_state = out + (size_t)SEQ * BATCH * VOCAB;
  float* out_cell  = out_state + BATCH * HID;

  void* args[] = { (void*)&x, (void*)&cell, (void*)&WT_g,
                   (void*)&W_xi, (void*)&W_xf, (void*)&W_xo, (void*)&W_xc,
                   (void*)&b_i, (void*)&b_f, (void*)&b_o, (void*)&b_c,
                   (void*)&H, (void*)&out_state, (void*)&out_cell, (void*)&bar };
  hipLaunchCooperativeKernel((void*)lstm_recurrence, dim3(32), dim3(256), args, 0, stream);

  // 79 n-tiles of 128 cover 10112 >= 10000 valid columns
  gemm_out<<<dim3(79, SEQ * BATCH / 128), 256, 0, stream>>>(H + BATCH * HID, WT_hq, b_q, out);
}